// Round 2
// baseline (154.700 us; speedup 1.0000x reference)
//
#include <hip/hip_runtime.h>

// SparseConv3D fused gather kernel.
// Key fact: out_idx is sorted ascending within each offset's pair list (np.nonzero),
// so pairs targeting a 128-row output tile form a contiguous range per offset.
// Prep kernel: bf16-convert weights + binary-search per-(offset,tile) range starts.
// Main kernel: per tile, center MFMA + per-offset 16-pair MFMA batches, all
// accumulated in an LDS fp32 tile (ds_add_f32) — zero global atomics, out written once.

typedef __bf16 bf16x8 __attribute__((ext_vector_type(8)));
typedef float f32x4 __attribute__((ext_vector_type(4)));

#define TROWS 128
#define LDSA 72   // bf16 row stride for A tiles (144B: frag b128 reads = 2-way bank alias, free)
#define OSTR 68   // f32 row stride for LDS out accumulator

__device__ __forceinline__ unsigned short f2bf(float f) {
    union { float f; unsigned int u; } v; v.f = f;
    unsigned int u = v.u;
    return (unsigned short)((u + 0x7FFFu + ((u >> 16) & 1u)) >> 16);  // RNE
}

__device__ __forceinline__ ushort4 cvt4(float4 v) {
    ushort4 b;
    b.x = f2bf(v.x); b.y = f2bf(v.y); b.z = f2bf(v.z); b.w = f2bf(v.w);
    return b;
}

// ---- prep: (a) weights f32 -> bf16 [27][cout][cin]; (b) tile range starts ----
__global__ __launch_bounds__(256) void sp3d_prep(
    const float* __restrict__ w, const int* __restrict__ nei,
    const int* __restrict__ sizes, unsigned short* __restrict__ wbf,
    int* __restrict__ starts, int P, int T, int wblocks)
{
    const int b = blockIdx.x;
    if (b < wblocks) {
        int id = b * 256 + threadIdx.x;            // one float4 per thread
        if (id < 27 * 64 * 16) {
            int k4 = id & 15, n = (id >> 4) & 63, tap = id >> 10;
            float4 v = *(const float4*)&w[n * 1728 + tap * 64 + k4 * 4];
            *(ushort4*)&wbf[(tap * 64 + n) * 64 + k4 * 4] = cvt4(v);
        }
    } else {
        int id = (b - wblocks) * 256 + threadIdx.x;
        if (id < 26 * (T + 1)) {
            int t = id % (T + 1), o = id / (T + 1);
            int target = t * TROWS;
            int lo = 0, hi = sizes[o];
            while (lo < hi) {                       // lower_bound on sorted out_idx
                int mid = (lo + hi) >> 1;
                if (nei[(o * P + mid) * 2] < target) lo = mid + 1; else hi = mid;
            }
            starts[o * (T + 1) + t] = lo;
        }
    }
}

// ---- main: one block per 128-row output tile ----
__global__ __launch_bounds__(256, 2) void sp3d_main(
    const float* __restrict__ sp, const float* __restrict__ bias,
    const int* __restrict__ nei, const unsigned short* __restrict__ wbf,
    const int* __restrict__ starts, float* __restrict__ out,
    int N, int P, int T)
{
    __shared__ unsigned short A[TROWS * LDSA];        // sp tile, bf16
    __shared__ float Ol[TROWS * OSTR];                // fp32 accumulator
    __shared__ unsigned short Ap[4][16 * LDSA];       // per-wave 16-pair gather slab

    const int t = threadIdx.x;
    const int w = t >> 6, lane = t & 63, ml = lane & 15, quad = lane >> 4;
    const int row0 = blockIdx.x * TROWS;
    const __bf16* Wg = (const __bf16*)wbf;

    // stage sp tile f32->bf16 (4 threads/row; per-instr 16 rows x 64B segments)
    {
        int r = t >> 2, c4 = t & 3;
        for (int g = 0; g < 2; ++g) {
            int rl = r + g * 64;
            long rowg = row0 + rl; if (rowg >= N) rowg = N - 1;  // clamp; masked at store
            #pragma unroll
            for (int i = 0; i < 4; ++i) {
                int col = (c4 + i * 4) * 4;
                float4 v = *(const float4*)&sp[rowg * 64 + col];
                *(ushort4*)&A[rl * LDSA + col] = cvt4(v);
            }
        }
    }
    __syncthreads();

    // center tap: each wave computes 32 rows x 64 cols, writes (not adds) to Ol
    {
        bf16x8 bf[4][2];
        #pragma unroll
        for (int nt = 0; nt < 4; ++nt)
            #pragma unroll
            for (int kh = 0; kh < 2; ++kh)
                bf[nt][kh] = *(const bf16x8*)&Wg[(13 * 64 + nt * 16 + ml) * 64 + kh * 32 + quad * 8];
        #pragma unroll
        for (int mt = 0; mt < 2; ++mt) {
            const __bf16* Ab = (const __bf16*)A + (w * 32 + mt * 16 + ml) * LDSA + quad * 8;
            bf16x8 a0 = *(const bf16x8*)Ab;
            bf16x8 a1 = *(const bf16x8*)(Ab + 32);
            #pragma unroll
            for (int nt = 0; nt < 4; ++nt) {
                f32x4 acc = {0.f, 0.f, 0.f, 0.f};
                acc = __builtin_amdgcn_mfma_f32_16x16x32_bf16(a0, bf[nt][0], acc, 0, 0, 0);
                acc = __builtin_amdgcn_mfma_f32_16x16x32_bf16(a1, bf[nt][1], acc, 0, 0, 0);
                #pragma unroll
                for (int rg = 0; rg < 4; ++rg)
                    Ol[(w * 32 + mt * 16 + quad * 4 + rg) * OSTR + nt * 16 + ml] = acc[rg];
            }
        }
    }
    __syncthreads();

    // neighbor taps: waves round-robin offsets; NO block barriers in this loop
    {
        __bf16* ApW = (__bf16*)Ap[w];
        for (int o = w; o < 26; o += 4) {
            int lo = starts[o * (T + 1) + blockIdx.x];
            int hi = starts[o * (T + 1) + blockIdx.x + 1];
            if (lo >= hi) continue;
            int tap = o + (o >= 13 ? 1 : 0);   // offsets enumeration skips center tap 13
            bf16x8 bf[4][2];
            #pragma unroll
            for (int nt = 0; nt < 4; ++nt)
                #pragma unroll
                for (int kh = 0; kh < 2; ++kh)
                    bf[nt][kh] = *(const bf16x8*)&Wg[(tap * 64 + nt * 16 + ml) * 64 + kh * 32 + quad * 8];

            for (int base = lo; base < hi; base += 16) {
                int cnt = hi - base; if (cnt > 16) cnt = 16;
                int pr = lane >> 2, part = lane & 3;   // 4 lanes per pair slot
                int outl_v = -1;
                if (pr < cnt) {
                    int2 e = *(const int2*)&nei[((long)o * P + base + pr) * 2];
                    outl_v = e.x - row0;
                    long inrow = e.y;
                    #pragma unroll
                    for (int i = 0; i < 4; ++i) {
                        float4 v = *(const float4*)&sp[inrow * 64 + part * 16 + i * 4];
                        *(ushort4*)&ApW[pr * LDSA + part * 16 + i * 4] = cvt4(v);
                    }
                } else {
                    ushort4 z = {0, 0, 0, 0};
                    #pragma unroll
                    for (int i = 0; i < 4; ++i)
                        *(ushort4*)&ApW[pr * LDSA + part * 16 + i * 4] = z;
                }
                // wave-internal LDS RAW: ds ops per wave are in-order; drain before frag reads
                __asm__ __volatile__("s_waitcnt lgkmcnt(0)" ::: "memory");
                bf16x8 a0 = *(const bf16x8*)&ApW[ml * LDSA + quad * 8];
                bf16x8 a1 = *(const bf16x8*)&ApW[ml * LDSA + 32 + quad * 8];
                #pragma unroll
                for (int nt = 0; nt < 4; ++nt) {
                    f32x4 acc = {0.f, 0.f, 0.f, 0.f};
                    acc = __builtin_amdgcn_mfma_f32_16x16x32_bf16(a0, bf[nt][0], acc, 0, 0, 0);
                    acc = __builtin_amdgcn_mfma_f32_16x16x32_bf16(a1, bf[nt][1], acc, 0, 0, 0);
                    #pragma unroll
                    for (int rg = 0; rg < 4; ++rg) {
                        int slot = quad * 4 + rg;              // C-layout row == pair slot
                        int ol = __shfl(outl_v, slot * 4);     // slot's part==0 loader lane
                        if (ol >= 0)
                            atomicAdd(&Ol[ol * OSTR + nt * 16 + ml], acc[rg]);  // ds_add_f32
                    }
                }
            }
        }
    }
    __syncthreads();

    // store out = Ol + bias
    {
        int r = t >> 2, c4 = t & 3;
        for (int g = 0; g < 2; ++g) {
            int rl = r + g * 64;
            long rowg = row0 + rl;
            if (rowg < N) {
                #pragma unroll
                for (int i = 0; i < 4; ++i) {
                    int col = (c4 + i * 4) * 4;
                    float4 bv = *(const float4*)&bias[col];
                    float4 res;
                    res.x = Ol[rl * OSTR + col + 0] + bv.x;
                    res.y = Ol[rl * OSTR + col + 1] + bv.y;
                    res.z = Ol[rl * OSTR + col + 2] + bv.z;
                    res.w = Ol[rl * OSTR + col + 3] + bv.w;
                    *(float4*)&out[rowg * 64 + col] = res;
                }
            }
        }
    }
}

extern "C" void kernel_launch(void* const* d_in, const int* in_sizes, int n_in,
                              void* d_out, int out_size, void* d_ws, size_t ws_size,
                              hipStream_t stream) {
    const float* sp    = (const float*)d_in[0];
    const float* w     = (const float*)d_in[1];
    const float* bias  = (const float*)d_in[2];
    const int*   nei   = (const int*)d_in[3];
    const int*   sizes = (const int*)d_in[4];
    float* out = (float*)d_out;

    const int N = in_sizes[0] / 64;
    const int P = in_sizes[3] / 52;            // [26][P][2]
    const int T = (N + TROWS - 1) / TROWS;

    unsigned short* wbf = (unsigned short*)d_ws;
    int* starts = (int*)((char*)d_ws + 27 * 64 * 64 * 2);  // after 221184B of weights

    const int wblocks = (27 * 64 * 16 + 255) / 256;        // 108
    const int sblocks = (26 * (T + 1) + 255) / 256;
    sp3d_prep<<<wblocks + sblocks, 256, 0, stream>>>(w, nei, sizes, wbf, starts, P, T, wblocks);
    sp3d_main<<<T, 256, 0, stream>>>(sp, bias, nei, wbf, starts, out, N, P, T);
}

// Round 3
// 153.345 us; speedup vs baseline: 1.0088x; 1.0088x over previous
//
#include <hip/hip_runtime.h>

// SparseConv3D fused gather kernel, v3 (latency-oriented rework).
// out_idx sorted per offset => pairs per (offset, 128-row tile) are contiguous ranges.
// Per tile-block: prefix-scan the 26 range sizes into one packed slot list,
// gather ALL pair rows in one cooperative burst (latency paid once), then per-offset
// MFMA batches read packed LDS rows and ds_add into an LDS fp32 accumulator.
// No global atomics; out written exactly once. 3 blocks/CU (LDS ~53KB).

typedef __bf16 bf16x8 __attribute__((ext_vector_type(8)));
typedef float f32x4 __attribute__((ext_vector_type(4)));

#define TROWS 128
#define SLOTS 128  // packed gather slots per chunk (chunk loop covers overflow)
#define LDSA 72    // bf16 row stride (144B): frag b128 reads = 2-way bank alias (free)
#define OSTR 66    // f32 row stride of LDS accumulator

__device__ __forceinline__ unsigned short f2bf(float f) {
    union { float f; unsigned int u; } v; v.f = f;
    unsigned int u = v.u;
    return (unsigned short)((u + 0x7FFFu + ((u >> 16) & 1u)) >> 16);  // RNE
}

__device__ __forceinline__ ushort4 cvt4(float4 v) {
    ushort4 b;
    b.x = f2bf(v.x); b.y = f2bf(v.y); b.z = f2bf(v.z); b.w = f2bf(v.w);
    return b;
}

// ---- prep: (a) weights f32 -> bf16 [27][cout][cin]; (b) per-(offset,tile) range starts ----
__global__ __launch_bounds__(256) void sp3d_prep(
    const float* __restrict__ w, const int* __restrict__ nei,
    const int* __restrict__ sizes, unsigned short* __restrict__ wbf,
    int* __restrict__ starts, int P, int T, int wblocks)
{
    const int b = blockIdx.x;
    if (b < wblocks) {
        int id = b * 256 + threadIdx.x;            // one float4 per thread
        if (id < 27 * 64 * 16) {
            int k4 = id & 15, n = (id >> 4) & 63, tap = id >> 10;
            float4 v = *(const float4*)&w[n * 1728 + tap * 64 + k4 * 4];
            *(ushort4*)&wbf[(tap * 64 + n) * 64 + k4 * 4] = cvt4(v);
        }
    } else {
        int id = (b - wblocks) * 256 + threadIdx.x;
        if (id < 26 * (T + 1)) {
            int t = id % (T + 1), o = id / (T + 1);
            int target = t * TROWS;
            int lo = 0, hi = sizes[o];
            while (lo < hi) {                       // lower_bound on sorted out_idx
                int mid = (lo + hi) >> 1;
                if (nei[(o * P + mid) * 2] < target) lo = mid + 1; else hi = mid;
            }
            starts[o * (T + 1) + t] = lo;
        }
    }
}

// ---- main: one block per 128-row output tile ----
__global__ __launch_bounds__(256, 3) void sp3d_main(
    const float* __restrict__ sp, const float* __restrict__ bias,
    const int* __restrict__ nei, const unsigned short* __restrict__ wbf,
    const int* __restrict__ starts, float* __restrict__ out,
    int N, int P, int T)
{
    __shared__ unsigned short Apack[SLOTS * LDSA];  // packed gather rows; doubles as center A tile
    __shared__ float Ol[TROWS * OSTR];              // fp32 accumulator
    __shared__ int sOut[SLOTS];                     // packed slot -> local out row
    __shared__ int sOff[27];                        // exclusive prefix of per-offset counts
    __shared__ int sLo[26];                         // per-offset global pair start

    const int t = threadIdx.x;
    const int w = t >> 6, lane = t & 63, ml = lane & 15, quad = lane >> 4;
    const int bid = blockIdx.x;
    const int row0 = bid * TROWS;
    const __bf16* Wg = (const __bf16*)wbf;

    // stage sp tile f32->bf16 into Apack rows 0..127 (center's A tile)
    {
        int r = t >> 2, c4 = t & 3;
        #pragma unroll
        for (int g = 0; g < 2; ++g) {
            int rl = r + g * 64;
            long rowg = row0 + rl; if (rowg >= N) rowg = N - 1;  // clamp; masked at store
            #pragma unroll
            for (int i = 0; i < 4; ++i) {
                int col = (c4 + i * 4) * 4;
                float4 v = *(const float4*)&sp[rowg * 64 + col];
                *(ushort4*)&Apack[rl * LDSA + col] = cvt4(v);
            }
        }
    }
    // wave 0: load 26 (lo,hi) ranges, exclusive-scan counts
    if (t < 64) {
        int o = t, lo = 0, cnt = 0;
        if (o < 26) {
            lo = starts[o * (T + 1) + bid];
            int hi = starts[o * (T + 1) + bid + 1];
            cnt = hi - lo;
            sLo[o] = lo;
        }
        int x = cnt;
        #pragma unroll
        for (int d = 1; d < 32; d <<= 1) {
            int y = __shfl_up(x, d);
            if (t >= d) x += y;
        }
        if (o < 26) sOff[o] = x - cnt;
        if (o == 25) sOff[26] = x;
    }
    __syncthreads();

    // center tap: wave w computes rows w*32..w*32+31, WRITES (not adds) Ol
    {
        bf16x8 bf[4][2];
        #pragma unroll
        for (int nt = 0; nt < 4; ++nt)
            #pragma unroll
            for (int kh = 0; kh < 2; ++kh)
                bf[nt][kh] = *(const bf16x8*)&Wg[(13 * 64 + nt * 16 + ml) * 64 + kh * 32 + quad * 8];
        #pragma unroll
        for (int mt = 0; mt < 2; ++mt) {
            const __bf16* Ab = (const __bf16*)Apack + (w * 32 + mt * 16 + ml) * LDSA + quad * 8;
            bf16x8 a0 = *(const bf16x8*)Ab;
            bf16x8 a1 = *(const bf16x8*)(Ab + 32);
            #pragma unroll
            for (int nt = 0; nt < 4; ++nt) {
                f32x4 acc = {0.f, 0.f, 0.f, 0.f};
                acc = __builtin_amdgcn_mfma_f32_16x16x32_bf16(a0, bf[nt][0], acc, 0, 0, 0);
                acc = __builtin_amdgcn_mfma_f32_16x16x32_bf16(a1, bf[nt][1], acc, 0, 0, 0);
                #pragma unroll
                for (int rg = 0; rg < 4; ++rg)
                    Ol[(w * 32 + mt * 16 + quad * 4 + rg) * OSTR + nt * 16 + ml] = acc[rg];
            }
        }
    }
    const int total = sOff[26];

    // chunk loop over packed slots
    for (int c0 = 0; c0 < total; c0 += SLOTS) {
        __syncthreads();  // prior Apack readers (center / prev batches) done
        const int nslot = min(SLOTS, total - c0);
        // cooperative gather: 4 lanes per slot, 2 passes; all loads issued concurrently
        {
            int part = t & 3, sl0 = t >> 2;
            #pragma unroll
            for (int pass = 0; pass < 2; ++pass) {
                int sl = sl0 + pass * 64;
                if (sl < nslot) {
                    int sg = c0 + sl;
                    int lo = 0, hi = 26;              // find o: sOff[o] <= sg < sOff[o+1]
                    while (hi - lo > 1) { int m = (lo + hi) >> 1; if (sOff[m] <= sg) lo = m; else hi = m; }
                    int o = lo;
                    int pairIdx = sLo[o] + (sg - sOff[o]);
                    int2 e = *(const int2*)&nei[((long)o * P + pairIdx) * 2];
                    if (part == 0) sOut[sl] = e.x - row0;
                    long inrow = e.y;
                    #pragma unroll
                    for (int i = 0; i < 4; ++i) {
                        float4 v = *(const float4*)&sp[inrow * 64 + part * 16 + i * 4];
                        *(ushort4*)&Apack[sl * LDSA + part * 16 + i * 4] = cvt4(v);
                    }
                }
            }
        }
        __syncthreads();
        // batches: waves round-robin offsets within this chunk; no barriers inside
        for (int o = w; o < 26; o += 4) {
            int s_begin = max(sOff[o], c0);
            int s_end   = min(sOff[o + 1], c0 + SLOTS);
            if (s_begin >= s_end) continue;
            int tap = o + (o >= 13 ? 1 : 0);  // offsets enumeration skips center tap 13
            bf16x8 bf[4][2];
            #pragma unroll
            for (int nt = 0; nt < 4; ++nt)
                #pragma unroll
                for (int kh = 0; kh < 2; ++kh)
                    bf[nt][kh] = *(const bf16x8*)&Wg[(tap * 64 + nt * 16 + ml) * 64 + kh * 32 + quad * 8];

            for (int base = s_begin; base < s_end; base += 16) {
                int bl = base - c0;
                int arow = bl + ml; if (arow > SLOTS - 1) arow = SLOTS - 1;  // clamp; masked below
                bf16x8 a0 = *(const bf16x8*)&Apack[arow * LDSA + quad * 8];
                bf16x8 a1 = *(const bf16x8*)&Apack[arow * LDSA + 32 + quad * 8];
                int olr[4];
                #pragma unroll
                for (int rg = 0; rg < 4; ++rg) {
                    int s_in = base + quad * 4 + rg;
                    olr[rg] = (s_in < s_end) ? sOut[s_in - c0] : -1;
                }
                f32x4 acc[4];
                #pragma unroll
                for (int nt = 0; nt < 4; ++nt) {
                    acc[nt] = f32x4{0.f, 0.f, 0.f, 0.f};
                    acc[nt] = __builtin_amdgcn_mfma_f32_16x16x32_bf16(a0, bf[nt][0], acc[nt], 0, 0, 0);
                    acc[nt] = __builtin_amdgcn_mfma_f32_16x16x32_bf16(a1, bf[nt][1], acc[nt], 0, 0, 0);
                }
                #pragma unroll
                for (int nt = 0; nt < 4; ++nt)
                    #pragma unroll
                    for (int rg = 0; rg < 4; ++rg)
                        if (olr[rg] >= 0)
                            atomicAdd(&Ol[olr[rg] * OSTR + nt * 16 + ml], acc[nt][rg]);  // ds_add_f32
            }
        }
    }
    __syncthreads();

    // store out = Ol + bias
    {
        int r = t >> 2, c4 = t & 3;
        #pragma unroll
        for (int g = 0; g < 2; ++g) {
            int rl = r + g * 64;
            long rowg = row0 + rl;
            if (rowg < N) {
                #pragma unroll
                for (int i = 0; i < 4; ++i) {
                    int col = (c4 + i * 4) * 4;
                    float4 bv = *(const float4*)&bias[col];
                    float4 res;
                    res.x = Ol[rl * OSTR + col + 0] + bv.x;
                    res.y = Ol[rl * OSTR + col + 1] + bv.y;
                    res.z = Ol[rl * OSTR + col + 2] + bv.z;
                    res.w = Ol[rl * OSTR + col + 3] + bv.w;
                    *(float4*)&out[rowg * 64 + col] = res;
                }
            }
        }
    }
}

extern "C" void kernel_launch(void* const* d_in, const int* in_sizes, int n_in,
                              void* d_out, int out_size, void* d_ws, size_t ws_size,
                              hipStream_t stream) {
    const float* sp    = (const float*)d_in[0];
    const float* w     = (const float*)d_in[1];
    const float* bias  = (const float*)d_in[2];
    const int*   nei   = (const int*)d_in[3];
    const int*   sizes = (const int*)d_in[4];
    float* out = (float*)d_out;

    const int N = in_sizes[0] / 64;
    const int P = in_sizes[3] / 52;            // [26][P][2]
    const int T = (N + TROWS - 1) / TROWS;

    unsigned short* wbf = (unsigned short*)d_ws;
    int* starts = (int*)((char*)d_ws + 27 * 64 * 64 * 2);  // after 221184B of weights

    const int wblocks = (27 * 64 * 16 + 255) / 256;        // 108
    const int sblocks = (26 * (T + 1) + 255) / 256;
    sp3d_prep<<<wblocks + sblocks, 256, 0, stream>>>(w, nei, sizes, wbf, starts, P, T, wblocks);
    sp3d_main<<<T, 256, 0, stream>>>(sp, bias, nei, wbf, starts, out, N, P, T);
}

// Round 4
// 124.326 us; speedup vs baseline: 1.2443x; 1.2334x over previous
//
#include <hip/hip_runtime.h>
#include <hip/hip_bf16.h>

// SparseConv3D v4: row-aligned im2col per 128-row tile, zero scatter.
// tbl[tap][m] = input row feeding output row m (or -1). out_tile = sum over 27
// taps of A_tap @ W_tap, accumulated in registers (center = tap 13, identity map).
// A frags: direct per-lane global loads + packed cvt (no LDS staging).
// W: LDS double-buffered per block, 8KB/tap shared by 4 waves.
// 33KB LDS + <=128 VGPR -> 4 blocks/CU -> all 782 blocks resident, one generation.

typedef __bf16 bf16x8 __attribute__((ext_vector_type(8)));
typedef float f32x4 __attribute__((ext_vector_type(4)));

#define TROWS 128
#define WSTR 72   // LDS weight row stride in bf16 (144B: frag reads 2-way bank alias = free)

__device__ __forceinline__ unsigned short f2bf(float f) {
    union { float f; unsigned int u; } v; v.f = f;
    unsigned int u = v.u;
    return (unsigned short)((u + 0x7FFFu + ((u >> 16) & 1u)) >> 16);  // RNE
}
__device__ __forceinline__ ushort4 cvt4(float4 v) {
    ushort4 b;
    b.x = f2bf(v.x); b.y = f2bf(v.y); b.z = f2bf(v.z); b.w = f2bf(v.w);
    return b;
}

// ---- prep: (a) weights f32 -> bf16 [27][cout][cin]; (b) per-(offset,tile) range starts ----
__global__ __launch_bounds__(256) void sp3d_prep(
    const float* __restrict__ w, const int* __restrict__ nei,
    const int* __restrict__ sizes, unsigned short* __restrict__ wbf,
    int* __restrict__ starts, int P, int T, int wblocks)
{
    const int b = blockIdx.x;
    if (b < wblocks) {
        int id = b * 256 + threadIdx.x;            // one float4 per thread
        if (id < 27 * 64 * 16) {
            int k4 = id & 15, n = (id >> 4) & 63, tap = id >> 10;
            float4 v = *(const float4*)&w[n * 1728 + tap * 64 + k4 * 4];
            *(ushort4*)&wbf[(tap * 64 + n) * 64 + k4 * 4] = cvt4(v);
        }
    } else {
        int id = (b - wblocks) * 256 + threadIdx.x;
        if (id < 26 * (T + 1)) {
            int t = id % (T + 1), o = id / (T + 1);
            int target = t * TROWS;
            int lo = 0, hi = sizes[o];
            while (lo < hi) {                       // lower_bound on sorted out_idx
                int mid = (lo + hi) >> 1;
                if (nei[(o * P + mid) * 2] < target) lo = mid + 1; else hi = mid;
            }
            starts[o * (T + 1) + t] = lo;
        }
    }
}

__device__ __forceinline__ bf16x8 pack8(float4 a, float4 b) {
    union { __hip_bfloat162 h[4]; bf16x8 v; } u;
    u.h[0] = __float22bfloat162_rn(float2{a.x, a.y});
    u.h[1] = __float22bfloat162_rn(float2{a.z, a.w});
    u.h[2] = __float22bfloat162_rn(float2{b.x, b.y});
    u.h[3] = __float22bfloat162_rn(float2{b.z, b.w});
    return u.v;
}

__device__ __forceinline__ void stage_w(unsigned short* dst, const unsigned short* wbf,
                                        int tap, int t) {
    // 256 threads copy one 64x64 bf16 tap (8KB) into padded LDS rows
    int n = t >> 2, kc = (t & 3) << 4;  // 16-bf16 chunk
    const uint4* src = (const uint4*)&wbf[(tap * 64 + n) * 64 + kc];
    uint4 a = src[0], b = src[1];
    *(uint4*)&dst[n * WSTR + kc] = a;
    *(uint4*)&dst[n * WSTR + kc + 8] = b;
}

// ---- main: one block per 128-row output tile; wave w owns rows w*32..w*32+31 ----
__global__ __launch_bounds__(256, 4) void sp3d_main(
    const float* __restrict__ sp, const float* __restrict__ bias,
    const int* __restrict__ nei, const unsigned short* __restrict__ wbf,
    const int* __restrict__ starts, float* __restrict__ out,
    int N, int P, int T)
{
    __shared__ unsigned short Wbuf[2][64 * WSTR];  // double-buffered tap weights
    __shared__ int tbl[27 * TROWS];                // tbl[tap][m] = in_row or -1
    __shared__ int sOff[27];
    __shared__ int sLo[26];

    const int t = threadIdx.x;
    const int w = t >> 6, lane = t & 63, ml = lane & 15, quad = lane >> 4;
    const int bid = blockIdx.x, row0 = bid * TROWS;

    // ---- build phase ----
    for (int i = t; i < 27 * TROWS; i += 256) tbl[i] = -1;
    if (t < TROWS) { int r = row0 + t; tbl[13 * TROWS + t] = (r < N) ? r : -1; }
    if (t < 64) {  // wave 0: load 26 (lo,hi) ranges, exclusive scan
        int o = t, lo = 0, cnt = 0;
        if (o < 26) {
            lo = starts[o * (T + 1) + bid];
            cnt = starts[o * (T + 1) + bid + 1] - lo;
            sLo[o] = lo;
        }
        int x = cnt;
        #pragma unroll
        for (int d = 1; d < 32; d <<= 1) {
            int y = __shfl_up(x, d);
            if (t >= d) x += y;
        }
        if (o < 26) sOff[o] = x - cnt;
        if (o == 25) sOff[26] = x;
    }
    __syncthreads();
    const int total = sOff[26];
    for (int s = t; s < total; s += 256) {
        int lo = 0, hi = 26;  // find o: sOff[o] <= s < sOff[o+1]
        while (hi - lo > 1) { int m = (lo + hi) >> 1; if (sOff[m] <= s) lo = m; else hi = m; }
        int o = lo;
        int2 e = *(const int2*)&nei[((long)o * P + sLo[o] + (s - sOff[o])) * 2];
        int tap = o + (o >= 13 ? 1 : 0);
        tbl[tap * TROWS + (e.x - row0)] = e.y;
    }
    stage_w(Wbuf[0], wbf, 0, t);
    __syncthreads();

    // ---- tap loop: register-accumulated, weight double-buffer, 1 barrier/tap ----
    f32x4 acc[2][4];
    #pragma unroll
    for (int mt = 0; mt < 2; ++mt)
        #pragma unroll
        for (int nt = 0; nt < 4; ++nt) acc[mt][nt] = f32x4{0.f, 0.f, 0.f, 0.f};

    for (int tap = 0; tap < 27; ++tap) {
        const int cur = tap & 1;
        if (tap + 1 < 27) stage_w(Wbuf[cur ^ 1], wbf, tap + 1, t);

        bf16x8 a[2][2];
        bool act[2];
        #pragma unroll
        for (int mt = 0; mt < 2; ++mt) {
            int idx = tbl[tap * TROWS + w * 32 + mt * 16 + ml];
            act[mt] = __any(idx >= 0);
            if (act[mt]) {
                float4 f0{0,0,0,0}, f1{0,0,0,0}, f2{0,0,0,0}, f3{0,0,0,0};
                if (idx >= 0) {
                    const float* rp = sp + (long)idx * 64 + quad * 8;
                    f0 = *(const float4*)rp;       f1 = *(const float4*)(rp + 4);
                    f2 = *(const float4*)(rp + 32); f3 = *(const float4*)(rp + 36);
                }
                a[mt][0] = pack8(f0, f1);
                a[mt][1] = pack8(f2, f3);
            }
        }
        if (act[0] | act[1]) {
            #pragma unroll
            for (int nt = 0; nt < 4; ++nt) {
                bf16x8 b0 = *(const bf16x8*)&Wbuf[cur][(nt * 16 + ml) * WSTR + quad * 8];
                bf16x8 b1 = *(const bf16x8*)&Wbuf[cur][(nt * 16 + ml) * WSTR + 32 + quad * 8];
                #pragma unroll
                for (int mt = 0; mt < 2; ++mt) {
                    if (act[mt]) {
                        acc[mt][nt] = __builtin_amdgcn_mfma_f32_16x16x32_bf16(a[mt][0], b0, acc[mt][nt], 0, 0, 0);
                        acc[mt][nt] = __builtin_amdgcn_mfma_f32_16x16x32_bf16(a[mt][1], b1, acc[mt][nt], 0, 0, 0);
                    }
                }
            }
        }
        __syncthreads();  // Wbuf[cur^1] writes visible; nobody reads cur after this
    }

    // ---- epilogue: acc + bias -> out (C layout: col = nt*16+ml, row = quad*4+rg) ----
    float bv[4];
    #pragma unroll
    for (int nt = 0; nt < 4; ++nt) bv[nt] = bias[nt * 16 + ml];
    #pragma unroll
    for (int mt = 0; mt < 2; ++mt)
        #pragma unroll
        for (int rg = 0; rg < 4; ++rg) {
            long row = row0 + w * 32 + mt * 16 + quad * 4 + rg;
            if (row < N) {
                #pragma unroll
                for (int nt = 0; nt < 4; ++nt)
                    out[row * 64 + nt * 16 + ml] = acc[mt][nt][rg] + bv[nt];
            }
        }
}

extern "C" void kernel_launch(void* const* d_in, const int* in_sizes, int n_in,
                              void* d_out, int out_size, void* d_ws, size_t ws_size,
                              hipStream_t stream) {
    const float* sp    = (const float*)d_in[0];
    const float* w     = (const float*)d_in[1];
    const float* bias  = (const float*)d_in[2];
    const int*   nei   = (const int*)d_in[3];
    const int*   sizes = (const int*)d_in[4];
    float* out = (float*)d_out;

    const int N = in_sizes[0] / 64;
    const int P = in_sizes[3] / 52;            // [26][P][2]
    const int T = (N + TROWS - 1) / TROWS;

    unsigned short* wbf = (unsigned short*)d_ws;
    int* starts = (int*)((char*)d_ws + 27 * 64 * 64 * 2);  // after 221184B of weights

    const int wblocks = (27 * 64 * 16 + 255) / 256;        // 108
    const int sblocks = (26 * (T + 1) + 255) / 256;
    sp3d_prep<<<wblocks + sblocks, 256, 0, stream>>>(w, nei, sizes, wbf, starts, P, T, wblocks);
    sp3d_main<<<T, 256, 0, stream>>>(sp, bias, nei, wbf, starts, out, N, P, T);
}